// Round 7
// baseline (405.768 us; speedup 1.0000x reference)
//
#include <hip/hip_runtime.h>

#define T_TOK 4096
#define H_DIM 512
#define I_DIM 1024
#define E_NUM 32
#define KTOP  2
#define CAP   512
#define NROWS (E_NUM * CAP)    // 16384
#define NPAIR (T_TOK * KTOP)   // 8192

typedef __attribute__((ext_vector_type(8))) short short8;    // 8 bf16 = 4 VGPRs
typedef __attribute__((ext_vector_type(4))) float float4v;
typedef __attribute__((ext_vector_type(4))) unsigned int uint4v;

typedef union { short8 s; uint4v u; } frag_u;

__device__ __forceinline__ unsigned short f2bf_rne(float f) {
  unsigned int u = __float_as_uint(f);
  u += 0x7FFFu + ((u >> 16) & 1u);
  return (unsigned short)(u >> 16);
}
__device__ __forceinline__ unsigned int pack_bf2(float a, float b) {
  return (unsigned int)f2bf_rne(a) | ((unsigned int)f2bf_rne(b) << 16);
}
// HW packed fp32->bf16 RNE convert
__device__ __forceinline__ unsigned int cvtpk(float a, float b) {
  unsigned int d;
  asm("v_cvt_pk_bf16_f32 %0, %1, %2" : "=v"(d) : "v"(a), "v"(b));
  return d;
}

#define GLOAD_LDS16(gptr, lptr)                                                         \
  __builtin_amdgcn_global_load_lds((const __attribute__((address_space(1))) unsigned int*)(gptr), \
                                   (__attribute__((address_space(3))) unsigned int*)(lptr), 16, 0, 0)

// ---------------- fused routing + gather: one wave per (token, slot) pair ------------
__global__ void k_route_gather(const float* __restrict__ hs, const int* __restrict__ idx,
                               const float* __restrict__ wts, int* __restrict__ counts,
                               int* __restrict__ slot_token, float* __restrict__ wslot,
                               unsigned short* __restrict__ xd) {
  const int i = blockIdx.x * 4 + (threadIdx.x >> 6);  // pair id 0..NPAIR-1
  const int lane = threadIdx.x & 63;
  const int e = idx[i];                // uniform (broadcast load)
  int p = 0;
  if (lane == 0) p = atomicAdd(counts + e, 1);
  p = __shfl(p, 0);
  if (p >= CAP) return;                // dropped pair: contributes nothing
  const int slot = e * CAP + p;
  if (lane == 0) {
    slot_token[slot] = i >> 1;         // KTOP == 2
    wslot[slot] = wts[i];
  }
  const float4v* src = (const float4v*)(hs + (size_t)(i >> 1) * H_DIM);
  float4v f0 = src[lane * 2];
  float4v f1 = src[lane * 2 + 1];
  uint4v v;
  v.x = pack_bf2(f0.x, f0.y); v.y = pack_bf2(f0.z, f0.w);
  v.z = pack_bf2(f1.x, f1.y); v.w = pack_bf2(f1.z, f1.w);
  *(uint4v*)(xd + (size_t)slot * H_DIM + lane * 8) = v;
  // NOTE: padded rows (p >= counts) keep workspace poison. Safe: MFMA output rows
  // are independent; poisoned rows are never stored to out.
}

// ---------------- GEMM1: xd[NROWS,H] x gate_up[E,2I,H]^T -> silu(g)*u -> act ---------
// 128x64 tile. A-fragments loaded DIRECTLY to registers (no LDS -> no 8-way bank
// conflict). B (fp32) staged via global_load_lds into 3 rotating 16KB buffers,
// depth-2 counted-vmcnt; converted bf16 at use with v_cvt_pk_bf16_f32.
// Per-iter vmem: 4 A-reg loads + 4 B-DMA; order A(t+1),B(t+2) -> uniform vmcnt(8).
__global__ __launch_bounds__(256, 2) void k_gemm1(const unsigned short* __restrict__ xd,
                                                  const float* __restrict__ gup,
                                                  const int* __restrict__ counts,
                                                  unsigned short* __restrict__ act) {
  __shared__ unsigned short lds[3 * 8192];  // per buf: Bg [0,4096) Bu [4096,8192) ushorts

  // expert<->XCD affinity (wg i -> XCD i%8): 4 experts x 16 col tiles x 4 row tiles per XCD
  const int bid = blockIdx.x;                      // 2048 blocks
  const int xcd = bid & 7, slot = bid >> 3;        // slot 0..255
  const int e = xcd + 8 * (slot >> 6);
  const int sub = slot & 63;
  const int c0 = (sub & 15) * 64;
  const int rt = sub >> 4;
  const int cnt = min(counts[e], CAP);
  if (rt * 128 >= cnt) return;
  const int r0 = e * CAP + rt * 128;

  const int tid = threadIdx.x;
  const int lane = tid & 63;
  const int wid = tid >> 6;
  const int wr = wid >> 1, wc = wid & 1;   // wave tile: 64 rows x 32 cols
  const int ml = lane & 15, kg = lane >> 4;

  // B staging (fp32): chunk ch in {tid, 256+tid}: n = ch>>3 (0..63), kcs = ch&7.
  // LDS slot n*8+kcs holds global 16B-chunk kc = kcs ^ (n&7) (pre-swizzled source).
  const int nB0 = tid >> 3, kcsB = tid & 7;
  const int kcB0 = kcsB ^ (nB0 & 7);
  const float* g_row0 = gup + (size_t)e * (2 * I_DIM * H_DIM) + (size_t)(c0 + nB0) * H_DIM + kcB0 * 4;
  const float* g_row1 = g_row0 + (size_t)32 * H_DIM;
  const float* u_row0 = g_row0 + (size_t)I_DIM * H_DIM;
  const float* u_row1 = u_row0 + (size_t)32 * H_DIM;
  const int dG0 = (wid * 64) * 8;          // wave-uniform LDS bases; DMA adds lane*16B
  const int dG1 = (256 + wid * 64) * 8;
  const int dU0 = 4096 + (wid * 64) * 8;
  const int dU1 = 4096 + (256 + wid * 64) * 8;

  // A-fragment global addresses (registers, no LDS)
  const unsigned short* a_base = xd + (size_t)r0 * H_DIM + kg * 8;

  float4v accg[4][2] = {};
  float4v accu[4][2] = {};
  short8 afc[4], afn[4];

  auto STAGE = [&](unsigned short* lb, int t) {
    GLOAD_LDS16(g_row0 + t * 32, lb + dG0);
    GLOAD_LDS16(g_row1 + t * 32, lb + dG1);
    GLOAD_LDS16(u_row0 + t * 32, lb + dU0);
    GLOAD_LDS16(u_row1 + t * 32, lb + dU1);
  };
  auto LOADA = [&](short8* af, int t) {
#pragma unroll
    for (int mi = 0; mi < 4; ++mi)
      af[mi] = *(const short8*)(a_base + (size_t)(wr * 64 + mi * 16 + ml) * H_DIM + t * 32);
  };
  auto COMPUTE = [&](const unsigned short* lb) {
    frag_u bg[2], bu[2];
#pragma unroll
    for (int ni = 0; ni < 2; ++ni) {
      const int n = wc * 32 + ni * 16 + ml;
      const int i0 = (n * 8 + ((2 * kg) ^ (n & 7))) * 8;
      const int i1 = (n * 8 + ((2 * kg + 1) ^ (n & 7))) * 8;
      float4v g0 = *(const float4v*)(lb + i0);
      float4v g1 = *(const float4v*)(lb + i1);
      bg[ni].u.x = cvtpk(g0.x, g0.y); bg[ni].u.y = cvtpk(g0.z, g0.w);
      bg[ni].u.z = cvtpk(g1.x, g1.y); bg[ni].u.w = cvtpk(g1.z, g1.w);
      float4v u0 = *(const float4v*)(lb + 4096 + i0);
      float4v u1 = *(const float4v*)(lb + 4096 + i1);
      bu[ni].u.x = cvtpk(u0.x, u0.y); bu[ni].u.y = cvtpk(u0.z, u0.w);
      bu[ni].u.z = cvtpk(u1.x, u1.y); bu[ni].u.w = cvtpk(u1.z, u1.w);
    }
#pragma unroll
    for (int mi = 0; mi < 4; ++mi)
#pragma unroll
      for (int ni = 0; ni < 2; ++ni) {
        accg[mi][ni] = __builtin_amdgcn_mfma_f32_16x16x32_bf16(afc[mi], bg[ni].s, accg[mi][ni], 0, 0, 0);
        accu[mi][ni] = __builtin_amdgcn_mfma_f32_16x16x32_bf16(afc[mi], bu[ni].s, accu[mi][ni], 0, 0, 0);
      }
  };

  unsigned short* b0 = lds;
  unsigned short* b1 = lds + 8192;
  unsigned short* b2 = lds + 16384;
  STAGE(b0, 0);
  LOADA(afc, 0);
  STAGE(b1, 1);
#pragma unroll 1
  for (int t = 0; t < 14; ++t) {           // NT = H/32 = 16
    asm volatile("s_waitcnt vmcnt(8)" ::: "memory");  // own B(t) landed (8 younger ops)
    __builtin_amdgcn_s_barrier();                      // -> all waves' B(t) landed
    __builtin_amdgcn_sched_barrier(0);
    LOADA(afn, t + 1);
    STAGE(b2, t + 2);                      // b2 last read at t-1 (pre-barrier): safe
    COMPUTE(b0);
#pragma unroll
    for (int mi = 0; mi < 4; ++mi) afc[mi] = afn[mi];
    unsigned short* tmp = b0; b0 = b1; b1 = b2; b2 = tmp;
  }
  asm volatile("s_waitcnt vmcnt(8)" ::: "memory");    // t = 14
  __builtin_amdgcn_s_barrier();
  __builtin_amdgcn_sched_barrier(0);
  LOADA(afn, 15);
  COMPUTE(b0);
#pragma unroll
  for (int mi = 0; mi < 4; ++mi) afc[mi] = afn[mi];
  asm volatile("s_waitcnt vmcnt(4)" ::: "memory");    // t = 15: B15's 4 younger = A15
  __builtin_amdgcn_s_barrier();
  __builtin_amdgcn_sched_barrier(0);
  COMPUTE(b1);

  // epilogue: act = silu(g)*u, bf16
#pragma unroll
  for (int mi = 0; mi < 4; ++mi) {
    const int row = r0 + wr * 64 + mi * 16 + kg * 4;
#pragma unroll
    for (int ni = 0; ni < 2; ++ni) {
      const int col = c0 + wc * 32 + ni * 16 + ml;
#pragma unroll
      for (int rj = 0; rj < 4; ++rj) {
        float g = accg[mi][ni][rj];
        float u = accu[mi][ni][rj];
        float a = (g / (1.0f + __expf(-g))) * u;
        act[(size_t)(row + rj) * I_DIM + col] = f2bf_rne(a);
      }
    }
  }
}

// ---------------- GEMM2 + combine: act x down^T, scaled-scatter into out -------------
// A in registers, B fp32 DMA depth-2 (3 x 8KB buffers), vmcnt(6) uniform.
// Epilogue: out[token[r]] += wslot[r] * acc  (f32 atomics; rows >= cnt skipped).
__global__ __launch_bounds__(256, 2) void k_gemm2c(const unsigned short* __restrict__ act,
                                                   const float* __restrict__ dwn,
                                                   const int* __restrict__ counts,
                                                   const int* __restrict__ slot_token,
                                                   const float* __restrict__ wslot,
                                                   float* __restrict__ out) {
  __shared__ unsigned short lds[3 * 4096];  // per buf: B [0,4096) ushorts = 8KB

  const int bid = blockIdx.x;                      // 1024 blocks
  const int xcd = bid & 7, slot = bid >> 3;        // slot 0..127
  const int e = xcd + 8 * (slot >> 5);
  const int sub = slot & 31;
  const int c0 = (sub & 7) * 64;
  const int rt = sub >> 3;
  const int cnt = min(counts[e], CAP);
  if (rt * 128 >= cnt) return;
  const int r0 = e * CAP + rt * 128;

  const int tid = threadIdx.x;
  const int lane = tid & 63;
  const int wid = tid >> 6;
  const int wr = wid >> 1, wc = wid & 1;
  const int ml = lane & 15, kg = lane >> 4;

  const int nB0 = tid >> 3, kcsB = tid & 7;
  const int kcB0 = kcsB ^ (nB0 & 7);
  const float* b_row0 = dwn + (size_t)e * (H_DIM * I_DIM) + (size_t)(c0 + nB0) * I_DIM + kcB0 * 4;
  const float* b_row1 = b_row0 + (size_t)32 * I_DIM;
  const int dB0 = (wid * 64) * 8;
  const int dB1 = (256 + wid * 64) * 8;

  const unsigned short* a_base = act + (size_t)r0 * I_DIM + kg * 8;

  float4v acc[4][2] = {};
  short8 afc[4], afn[4];

  auto STAGE = [&](unsigned short* lb, int t) {
    GLOAD_LDS16(b_row0 + t * 32, lb + dB0);
    GLOAD_LDS16(b_row1 + t * 32, lb + dB1);
  };
  auto LOADA = [&](short8* af, int t) {
#pragma unroll
    for (int mi = 0; mi < 4; ++mi)
      af[mi] = *(const short8*)(a_base + (size_t)(wr * 64 + mi * 16 + ml) * I_DIM + t * 32);
  };
  auto COMPUTE = [&](const unsigned short* lb) {
    frag_u bf[2];
#pragma unroll
    for (int ni = 0; ni < 2; ++ni) {
      const int n = wc * 32 + ni * 16 + ml;
      const int i0 = (n * 8 + ((2 * kg) ^ (n & 7))) * 8;
      const int i1 = (n * 8 + ((2 * kg + 1) ^ (n & 7))) * 8;
      float4v f0 = *(const float4v*)(lb + i0);
      float4v f1 = *(const float4v*)(lb + i1);
      bf[ni].u.x = cvtpk(f0.x, f0.y); bf[ni].u.y = cvtpk(f0.z, f0.w);
      bf[ni].u.z = cvtpk(f1.x, f1.y); bf[ni].u.w = cvtpk(f1.z, f1.w);
    }
#pragma unroll
    for (int mi = 0; mi < 4; ++mi)
#pragma unroll
      for (int ni = 0; ni < 2; ++ni)
        acc[mi][ni] = __builtin_amdgcn_mfma_f32_16x16x32_bf16(afc[mi], bf[ni].s, acc[mi][ni], 0, 0, 0);
  };

  unsigned short* b0 = lds;
  unsigned short* b1 = lds + 4096;
  unsigned short* b2 = lds + 8192;
  STAGE(b0, 0);
  LOADA(afc, 0);
  STAGE(b1, 1);
#pragma unroll 1
  for (int t = 0; t < 30; ++t) {           // NT = I/32 = 32
    asm volatile("s_waitcnt vmcnt(6)" ::: "memory");
    __builtin_amdgcn_s_barrier();
    __builtin_amdgcn_sched_barrier(0);
    LOADA(afn, t + 1);
    STAGE(b2, t + 2);
    COMPUTE(b0);
#pragma unroll
    for (int mi = 0; mi < 4; ++mi) afc[mi] = afn[mi];
    unsigned short* tmp = b0; b0 = b1; b1 = b2; b2 = tmp;
  }
  asm volatile("s_waitcnt vmcnt(6)" ::: "memory");    // t = 30
  __builtin_amdgcn_s_barrier();
  __builtin_amdgcn_sched_barrier(0);
  LOADA(afn, 31);
  COMPUTE(b0);
#pragma unroll
  for (int mi = 0; mi < 4; ++mi) afc[mi] = afn[mi];
  asm volatile("s_waitcnt vmcnt(4)" ::: "memory");    // t = 31: 4 younger = A31
  __builtin_amdgcn_s_barrier();
  __builtin_amdgcn_sched_barrier(0);
  COMPUTE(b1);

  // fused combine epilogue: out[token] += w * y  (valid rows only)
#pragma unroll
  for (int mi = 0; mi < 4; ++mi) {
    const int rbase = r0 + wr * 64 + mi * 16 + kg * 4;
#pragma unroll
    for (int rj = 0; rj < 4; ++rj) {
      const int r = rbase + rj;
      if ((r - e * CAP) < cnt) {
        const float w = wslot[r];
        const int tok = slot_token[r];
#pragma unroll
        for (int ni = 0; ni < 2; ++ni) {
          const int col = c0 + wc * 32 + ni * 16 + ml;
          atomicAdd(out + (size_t)tok * H_DIM + col, w * acc[mi][ni][rj]);
        }
      }
    }
  }
}

extern "C" void kernel_launch(void* const* d_in, const int* in_sizes, int n_in,
                              void* d_out, int out_size, void* d_ws, size_t ws_size,
                              hipStream_t stream) {
  const float* hs  = (const float*)d_in[0];  // [T,H]
  const int*   idx = (const int*)d_in[1];    // [T,K]
  const float* wts = (const float*)d_in[2];  // [T,K]
  const float* gup = (const float*)d_in[3];  // [E,2I,H]
  const float* dwn = (const float*)d_in[4];  // [E,H,I]
  float* out = (float*)d_out;                // [T,H]

  char* ws = (char*)d_ws;
  int*   counts     = (int*)ws;                             // 1 KB region
  int*   slot_token = (int*)(ws + 1024);                    // 64 KB
  float* wslot      = (float*)(ws + 1024 + 65536);          // 64 KB
  unsigned short* xd  = (unsigned short*)(ws + 1024 + 131072);   // 16.8 MB
  unsigned short* act = xd + (size_t)NROWS * H_DIM;              // 33.6 MB

  hipMemsetAsync(counts, 0, E_NUM * sizeof(int), stream);
  hipMemsetAsync(out, 0, (size_t)T_TOK * H_DIM * sizeof(float), stream);
  k_route_gather<<<NPAIR / 4, 256, 0, stream>>>(hs, idx, wts, counts, slot_token, wslot, xd);
  k_gemm1<<<2048, 256, 0, stream>>>(xd, gup, counts, act);
  k_gemm2c<<<1024, 256, 0, stream>>>(act, dwn, counts, slot_token, wslot, out);
}